// Round 16
// baseline (56.904 us; speedup 1.0000x reference)
//
#include <hip/hip_runtime.h>
#include <hip/hip_bf16.h>
#include <math.h>

#define TB 4096   // batch
#define TN 39     // fields
#define TM 32     // embed dim
#define TD 32     // product layer dim
#define TH 400    // hidden width
#define BN_EPS 1e-3f

#define KT0 2     // layer-0 K=64  -> 2 chunks of K32
#define KTH 13    // layers 1/2 K=400 padded to 416 -> 13 chunks of K32
#define ESP (TN * TM + 8)   // e_s row stride: +8 floats -> rs rows hit distinct banks

typedef __attribute__((ext_vector_type(8))) short bf16x8;
typedef __attribute__((ext_vector_type(4))) float f32x4;

// ---- fp32 -> bf16 hi/lo split ----
__device__ __forceinline__ ushort bf16_rn(float x) {
    __hip_bfloat16 h = __float2bfloat16(x);
    union { __hip_bfloat16 b; ushort u; } c; c.b = h; return c.u;
}
__device__ __forceinline__ void split2(float x, ushort& hi, ushort& lo) {
    unsigned xb = __float_as_uint(x);
    unsigned hb = xb & 0xFFFF0000u;
    hi = (ushort)(hb >> 16);
    lo = bf16_rn(x - __uint_as_float(hb));
}

// async global->LDS, 16 B per lane: LDS dst is wave-uniform base + lane*16,
// global src is per-lane.
__device__ __forceinline__ void gload_lds16(const void* g, void* l) {
    __builtin_amdgcn_global_load_lds(
        (const __attribute__((address_space(1))) void*)g,
        (__attribute__((address_space(3))) void*)l,
        16, 0, 0);
}

// MFMA 16x16x32 bf16 fragment layout. Panels: [tile16][kt32][lane 64][j 8]
// ushorts; one (tile,kt) chunk = 512 ushorts = 1 KB.
__device__ __forceinline__ size_t panel_idx(int p, int k, int KT) {
    int lane_ = (p & 15) + 16 * ((k >> 2) & 3);
    int j_    = (k & 3) + 4 * ((k >> 4) & 1);
    return (((size_t)((p >> 4) * KT + (k >> 5)) * 64) + lane_) * 8 + j_;
}

// ---------------------------------------------------------------------------
// Front kernel:
//  blocks [0,1024): gather (async gload_lds) + l_z (d-tiled x4) + l_p -> A0
//  blocks [1024,1422): prepack W0/W1/W2 -> B panels; fold BN -> AC arrays
// ---------------------------------------------------------------------------
__global__ __launch_bounds__(256) void fused_front_kernel(
    const int*   __restrict__ fidx,
    const float* __restrict__ emb,
    const float* __restrict__ lin_w,
    const float* __restrict__ quad_w,
    const float* __restrict__ W0, const float* __restrict__ W1, const float* __restrict__ W2,
    const float* __restrict__ b0_, const float* __restrict__ g0_, const float* __restrict__ be0_,
    const float* __restrict__ rm0_, const float* __restrict__ rv0_,
    const float* __restrict__ b1_, const float* __restrict__ g1_, const float* __restrict__ be1_,
    const float* __restrict__ rm1_, const float* __restrict__ rv1_,
    const float* __restrict__ b2_, const float* __restrict__ g2_, const float* __restrict__ be2_,
    const float* __restrict__ rm2_, const float* __restrict__ rv2_,
    ushort* __restrict__ A0h, ushort* __restrict__ A0l,
    ushort* __restrict__ B0h, ushort* __restrict__ B0l,
    ushort* __restrict__ B1h, ushort* __restrict__ B1l,
    ushort* __restrict__ B2h, ushort* __restrict__ B2l,
    float* __restrict__ AC)
{
    if (blockIdx.x >= TB / 4) {
        int tid = (blockIdx.x - TB / 4) * 256 + threadIdx.x;
        const int NW0 = 64 * 112, NW = 416 * 112;
        if (tid < NW0 + 2 * NW) {
            const float* W; ushort *Ph, *Pl; int k, n4, K, KT;
            if (tid < NW0) {
                W = W0; Ph = B0h; Pl = B0l; k = tid / 112; n4 = tid % 112; K = 64; KT = KT0;
            } else if (tid < NW0 + NW) {
                int u = tid - NW0;
                W = W1; Ph = B1h; Pl = B1l; k = u / 112; n4 = u % 112; K = TH; KT = KTH;
            } else {
                int u = tid - NW0 - NW;
                W = W2; Ph = B2h; Pl = B2l; k = u / 112; n4 = u % 112; K = TH; KT = KTH;
            }
            int n0 = n4 * 4;
            float4 w = make_float4(0.f, 0.f, 0.f, 0.f);
            if (k < K && n0 < TH)
                w = *(const float4*)&W[(size_t)k * TH + n0];
            float vals[4] = {w.x, w.y, w.z, w.w};
            #pragma unroll
            for (int i = 0; i < 4; ++i) {
                ushort hi, lo; split2(vals[i], hi, lo);
                size_t idx = panel_idx(n0 + i, k, KT);
                Ph[idx] = hi; Pl[idx] = lo;
            }
        } else if (tid < NW0 + 2 * NW + 3 * 448) {
            int u = tid - NW0 - 2 * NW;
            int layer = u / 448, h = u % 448;
            const float *gp, *bep, *rmp, *rvp, *bp;
            if (layer == 0)      { gp = g0_; bep = be0_; rmp = rm0_; rvp = rv0_; bp = b0_; }
            else if (layer == 1) { gp = g1_; bep = be1_; rmp = rm1_; rvp = rv1_; bp = b1_; }
            else                 { gp = g2_; bep = be2_; rmp = rm2_; rvp = rv2_; bp = b2_; }
            float aj = 0.f, cj = 0.f;
            if (h < TH) {
                aj = gp[h] * rsqrtf(rvp[h] + BN_EPS);
                cj = (bp[h] - rmp[h]) * aj + bep[h];
            }
            AC[layer * 896 + h] = aj;
            AC[layer * 896 + 448 + h] = cj;
        }
        return;
    }

    // ---------------- gather + product path ----------------
    constexpr int R = 4;
    __shared__ float e_s[R][ESP];       // rows padded; data region contiguous
    __shared__ int   idx_s[R][TN];
    __shared__ float s_s[R][TN];

    const int t  = threadIdx.x;
    const int b0 = blockIdx.x * R;
    const int w  = t >> 6;

    if (t < R * TN) {
        int r = t / TN, n = t - r * TN;
        idx_s[r][n] = fidx[(b0 + r) * TN + n];
    }
    __syncthreads();

    // Gather via async global_load_lds: k4 = t covers [0,256); wave w's 64
    // lanes are contiguous 1 KB at e_s[r] + w*1024B. Tail k4 = 256+t (t<56)
    // handled under exec mask. The single __syncthreads drains all loads.
    #pragma unroll
    for (int r = 0; r < R; ++r) {
        {
            int n = t >> 3;
            long long gb = (long long)idx_s[r][n] * TM + ((t & 7) << 2);
            gload_lds16(&emb[gb], &e_s[r][w * 256]);
        }
        if (t < 56) {
            int k4 = 256 + t;
            int n = k4 >> 3;
            long long gb = (long long)idx_s[r][n] * TM + ((k4 & 7) << 2);
            gload_lds16(&emb[gb], &e_s[r][1024]);
        }
    }
    __syncthreads();

    // l_z (d-tiled x4): thread (dg = t>>5, rs = (t>>3)&3, j = t&7) computes
    // d = dg*4+{0..3} for row rs. Each e4 read once per i (was 4x).
    // Per-(d,j,r) FMA order and j-shuffle tree identical to the verified
    // round-2 form -> bitwise-identical A0 panels.
    {
        const int dg = t >> 5, rs = (t >> 3) & 3, j = t & 7;
        float acc[4] = {0.f, 0.f, 0.f, 0.f};
        const float* lwb = lin_w + (size_t)(dg * 4) * (TN * TM) + j * 4;
        const float* er  = &e_s[rs][j * 4];
        #pragma unroll 4
        for (int i = 0; i < TN; ++i) {
            float4 e4 = *(const float4*)&er[i * 32];
            #pragma unroll
            for (int di = 0; di < 4; ++di) {
                float4 lw = *(const float4*)&lwb[(size_t)di * (TN * TM) + i * 32];
                acc[di] = fmaf(lw.x, e4.x, acc[di]);
                acc[di] = fmaf(lw.y, e4.y, acc[di]);
                acc[di] = fmaf(lw.z, e4.z, acc[di]);
                acc[di] = fmaf(lw.w, e4.w, acc[di]);
            }
        }
        #pragma unroll
        for (int off = 1; off < 8; off <<= 1)
            #pragma unroll
            for (int di = 0; di < 4; ++di)
                acc[di] += __shfl_xor(acc[di], off);
        if (j == 0) {
            #pragma unroll
            for (int di = 0; di < 4; ++di) {
                ushort hi, lo; split2(acc[di], hi, lo);
                size_t idx = panel_idx(b0 + rs, dg * 4 + di, KT0);
                A0h[idx] = hi; A0l[idx] = lo;
            }
        }
    }

    // s[n] = sum_m e^2
    {
        int r = t >> 6, lane = t & 63;
        if (lane < TN) {
            float s = 0.f;
            #pragma unroll
            for (int mm = 0; mm < TM; ++mm) {
                float v = e_s[r][lane * TM + ((lane + mm) & 31)];
                s = fmaf(v, v, s);
            }
            s_s[r][lane] = s;
        }
    }
    __syncthreads();

    // l_p
    if (t < R * TD) {
        int r = t >> 5, d = t & 31;
        float accv = 0.f;
        for (int n = 0; n < TN; ++n) {
            float q = quad_w[d * TN + n];
            accv = fmaf(s_s[r][n], q * q, accv);
        }
        ushort hi, lo; split2(accv, hi, lo);
        size_t idx = panel_idx(b0 + r, TD + d, KT0);
        A0h[idx] = hi; A0l[idx] = lo;
    }
}

// ---------------------------------------------------------------------------
// GEMM v7 (round-10 body, unchanged): 64x64 tile, 4 waves, XCD swizzle,
// per-kt LDS staging via global_load_lds (double-buffered).
// ---------------------------------------------------------------------------
template <int KT, int OUTMODE>
__global__ __launch_bounds__(256) void gemm_layer_v7(
    const ushort* __restrict__ Ah, const ushort* __restrict__ Al,
    const ushort* __restrict__ Bh, const ushort* __restrict__ Bl,
    const float* __restrict__ ACl,
    ushort* __restrict__ Nh, ushort* __restrict__ Nl,
    const float* __restrict__ Wout,
    float* __restrict__ P)
{
    __shared__ ushort stage[2][16 * 512];   // 2 x 16 KB double buffer

    const int lane = threadIdx.x & 63;
    const int wv   = threadIdx.x >> 6;      // 0..3
    const int msel = wv >> 1;               // M half
    const int nsel = wv & 1;                // N half

    // XCD-aware bijective swizzle over 448 blocks (bm 0..63, bn 0..6)
    const int orig = blockIdx.x;
    const int xcd  = orig & 7;
    const int slot = orig >> 3;             // 0..55
    const int bm   = (slot & 7) * 8 + xcd;  // 0..63
    const int bn   = slot >> 3;             // 0..6

    // Per-wave staging assignment: 4 chunks each
    const ushort* csrc[4];
    int coff[4];
    #pragma unroll
    for (int i = 0; i < 4; ++i) {
        int c = wv * 4 + i;
        bool isA = c < 8;
        int tl  = isA ? (c >> 1) : ((c - 8) >> 1);
        bool lo = c & 1;
        const ushort* base = isA ? (lo ? Al : Ah) : (lo ? Bl : Bh);
        int tileIdx = isA ? (bm * 4 + tl) : (bn * 4 + tl);
        csrc[i] = base + (size_t)tileIdx * KT * 512 + (size_t)lane * 8;
        coff[i] = c * 512;
    }

    f32x4 acc[2][2];
    #pragma unroll
    for (int m = 0; m < 2; ++m)
        #pragma unroll
        for (int n = 0; n < 2; ++n)
            acc[m][n] = (f32x4){0.f, 0.f, 0.f, 0.f};

    // prologue: stage kt=0 into buf0
    #pragma unroll
    for (int i = 0; i < 4; ++i)
        gload_lds16(csrc[i], &stage[0][coff[i]]);
    __syncthreads();

    for (int kt = 0; kt < KT; ++kt) {
        const int cur = kt & 1;
        if (kt + 1 < KT) {
            #pragma unroll
            for (int i = 0; i < 4; ++i)
                gload_lds16(csrc[i] + (size_t)(kt + 1) * 512,
                            &stage[cur ^ 1][coff[i]]);
        }
        const ushort* L = &stage[cur][0];
        bf16x8 ah[2], al[2], bh[2], bl[2];
        #pragma unroll
        for (int m = 0; m < 2; ++m) {
            int mt = msel * 2 + m;
            ah[m] = *(const bf16x8*)&L[(mt * 2 + 0) * 512 + lane * 8];
            al[m] = *(const bf16x8*)&L[(mt * 2 + 1) * 512 + lane * 8];
        }
        #pragma unroll
        for (int n = 0; n < 2; ++n) {
            int nt = nsel * 2 + n;
            bh[n] = *(const bf16x8*)&L[(8 + nt * 2 + 0) * 512 + lane * 8];
            bl[n] = *(const bf16x8*)&L[(8 + nt * 2 + 1) * 512 + lane * 8];
        }
        #pragma unroll
        for (int m = 0; m < 2; ++m)
            #pragma unroll
            for (int n = 0; n < 2; ++n) {
                acc[m][n] = __builtin_amdgcn_mfma_f32_16x16x32_bf16(ah[m], bh[n], acc[m][n], 0, 0, 0);
                acc[m][n] = __builtin_amdgcn_mfma_f32_16x16x32_bf16(ah[m], bl[n], acc[m][n], 0, 0, 0);
                acc[m][n] = __builtin_amdgcn_mfma_f32_16x16x32_bf16(al[m], bh[n], acc[m][n], 0, 0, 0);
            }
        __syncthreads();   // drains staged loads; protects buffer swap
    }

    const int col = lane & 15, rq = (lane >> 4) << 2;

    if constexpr (OUTMODE == 0) {
        float (*ysm)[68] = (float (*)[68])(void*)&stage[0][0];  // 17.4 KB alias
        #pragma unroll
        for (int m = 0; m < 2; ++m)
            #pragma unroll
            for (int n = 0; n < 2; ++n) {
                int h = bn * 64 + (nsel * 2 + n) * 16 + col;
                float aj = ACl[h], cj = ACl[448 + h];
                #pragma unroll
                for (int r = 0; r < 4; ++r)
                    ysm[msel * 32 + m * 16 + rq + r][(nsel * 2 + n) * 16 + col] =
                        fmaxf(fmaf(acc[m][n][r], aj, cj), 0.f);
            }
        __syncthreads();

        const int ck = wv & 1;
        const int kt32 = bn * 2 + ck;
        if (kt32 < KTH) {
            #pragma unroll
            for (int mi = 0; mi < 2; ++mi) {
                int mtl = (wv >> 1) * 2 + mi;    // 0..3
                int row_l = mtl * 16 + (lane & 15);
                int kb = ck * 32 + rq;
                float4 v0 = *(const float4*)&ysm[row_l][kb];
                float4 v1 = *(const float4*)&ysm[row_l][kb + 16];
                ushort h_[8], l_[8];
                split2(v0.x, h_[0], l_[0]); split2(v0.y, h_[1], l_[1]);
                split2(v0.z, h_[2], l_[2]); split2(v0.w, h_[3], l_[3]);
                split2(v1.x, h_[4], l_[4]); split2(v1.y, h_[5], l_[5]);
                split2(v1.z, h_[6], l_[6]); split2(v1.w, h_[7], l_[7]);
                uint4 H, L2;
                H.x = (uint)h_[0] | ((uint)h_[1] << 16);
                H.y = (uint)h_[2] | ((uint)h_[3] << 16);
                H.z = (uint)h_[4] | ((uint)h_[5] << 16);
                H.w = (uint)h_[6] | ((uint)h_[7] << 16);
                L2.x = (uint)l_[0] | ((uint)l_[1] << 16);
                L2.y = (uint)l_[2] | ((uint)l_[3] << 16);
                L2.z = (uint)l_[4] | ((uint)l_[5] << 16);
                L2.w = (uint)l_[6] | ((uint)l_[7] << 16);
                size_t base = (((size_t)(bm * 4 + mtl) * KTH + kt32) * 64 + lane) * 8;
                *(uint4*)(Nh + base) = H;
                *(uint4*)(Nl + base) = L2;
            }
        }
    } else {
        // Fused final-layer epilogue: y = relu(bn(acc)); partial = sum_h y*Wout[h]
        float partial[2][4] = {{0.f,0.f,0.f,0.f},{0.f,0.f,0.f,0.f}};
        #pragma unroll
        for (int m = 0; m < 2; ++m)
            #pragma unroll
            for (int n = 0; n < 2; ++n) {
                int h = bn * 64 + (nsel * 2 + n) * 16 + col;
                float aj = ACl[h], cj = ACl[448 + h];
                float wv_ = (h < TH) ? Wout[h] : 0.f;
                #pragma unroll
                for (int r = 0; r < 4; ++r) {
                    float y = fmaxf(fmaf(acc[m][n][r], aj, cj), 0.f);
                    partial[m][r] = fmaf(y, wv_, partial[m][r]);
                }
            }
        #pragma unroll
        for (int off = 1; off < 16; off <<= 1)
            #pragma unroll
            for (int m = 0; m < 2; ++m)
                #pragma unroll
                for (int r = 0; r < 4; ++r)
                    partial[m][r] += __shfl_xor(partial[m][r], off);
        if (col == 0) {
            #pragma unroll
            for (int m = 0; m < 2; ++m)
                #pragma unroll
                for (int r = 0; r < 4; ++r)
                    P[(size_t)(bm * 64 + msel * 32 + m * 16 + rq + r) * 16
                      + bn * 2 + nsel] = partial[m][r];
        }
    }
}

// ---------------------------------------------------------------------------
// fin: out[row] = sigmoid(sum_{i<14} P[row][i] + bout), float4 loads
// ---------------------------------------------------------------------------
__global__ __launch_bounds__(256) void fin_kernel(
    const float* __restrict__ P, const float* __restrict__ bout,
    float* __restrict__ out)
{
    int row = blockIdx.x * 256 + threadIdx.x;
    const float4* p = (const float4*)(P + (size_t)row * 16);
    float4 p0 = p[0], p1 = p[1], p2 = p[2], p3 = p[3];
    float s = bout[0]
            + p0.x + p0.y + p0.z + p0.w
            + p1.x + p1.y + p1.z + p1.w
            + p2.x + p2.y + p2.z + p2.w
            + p3.x + p3.y;
    out[row] = 1.f / (1.f + expf(-s));
}

// ---------------------------------------------------------------------------
extern "C" void kernel_launch(void* const* d_in, const int* in_sizes, int n_in,
                              void* d_out, int out_size, void* d_ws, size_t ws_size,
                              hipStream_t stream) {
    const int*   fidx   = (const int*)  d_in[0];
    const float* emb    = (const float*)d_in[2];
    const float* lin_w  = (const float*)d_in[3];
    const float* quad_w = (const float*)d_in[4];

    const float* W0  = (const float*)d_in[5];
    const float* b0  = (const float*)d_in[6];
    const float* g0  = (const float*)d_in[7];
    const float* be0 = (const float*)d_in[8];
    const float* rm0 = (const float*)d_in[9];
    const float* rv0 = (const float*)d_in[10];

    const float* W1  = (const float*)d_in[11];
    const float* b1  = (const float*)d_in[12];
    const float* g1  = (const float*)d_in[13];
    const float* be1 = (const float*)d_in[14];
    const float* rm1 = (const float*)d_in[15];
    const float* rv1 = (const float*)d_in[16];

    const float* W2  = (const float*)d_in[17];
    const float* b2  = (const float*)d_in[18];
    const float* g2  = (const float*)d_in[19];
    const float* be2 = (const float*)d_in[20];
    const float* rm2 = (const float*)d_in[21];
    const float* rv2 = (const float*)d_in[22];

    const float* Wout = (const float*)d_in[23];
    const float* bout = (const float*)d_in[24];

    const size_t SZ_A0 = (size_t)256 * KT0 * 512;
    const size_t SZ_A  = (size_t)256 * KTH * 512;
    const size_t SZ_B0 = (size_t)28  * KT0 * 512;
    const size_t SZ_B  = (size_t)28  * KTH * 512;

    ushort* p = (ushort*)d_ws;
    ushort *A0h = p; p += SZ_A0; ushort *A0l = p; p += SZ_A0;
    ushort *A1h = p; p += SZ_A;  ushort *A1l = p; p += SZ_A;
    ushort *A2h = p; p += SZ_A;  ushort *A2l = p; p += SZ_A;
    ushort *B0h = p; p += SZ_B0; ushort *B0l = p; p += SZ_B0;
    ushort *B1h = p; p += SZ_B;  ushort *B1l = p; p += SZ_B;
    ushort *B2h = p; p += SZ_B;  ushort *B2l = p; p += SZ_B;
    float*  AC  = (float*)p;                 // 3 * 896 floats
    float*  Pst = AC + 3 * 896;              // 4096 x 16 partials

    fused_front_kernel<<<TB / 4 + 398, 256, 0, stream>>>(
        fidx, emb, lin_w, quad_w, W0, W1, W2,
        b0, g0, be0, rm0, rv0,
        b1, g1, be1, rm1, rv1,
        b2, g2, be2, rm2, rv2,
        A0h, A0l, B0h, B0l, B1h, B1l, B2h, B2l, AC);

    gemm_layer_v7<KT0, 0><<<448, 256, 0, stream>>>(
        A0h, A0l, B0h, B0l, AC + 0, A1h, A1l, nullptr, nullptr);
    gemm_layer_v7<KTH, 0><<<448, 256, 0, stream>>>(
        A1h, A1l, B1h, B1l, AC + 896, A2h, A2l, nullptr, nullptr);
    gemm_layer_v7<KTH, 1><<<448, 256, 0, stream>>>(
        A2h, A2l, B2h, B2l, AC + 1792, nullptr, nullptr, Wout, Pst);

    fin_kernel<<<TB / 256, 256, 0, stream>>>(Pst, bout, (float*)d_out);
}

// Round 17
// 48.955 us; speedup vs baseline: 1.1624x; 1.1624x over previous
//
#include <hip/hip_runtime.h>
#include <hip/hip_bf16.h>
#include <math.h>

#define TB 4096   // batch
#define TN 39     // fields
#define TM 32     // embed dim
#define TD 32     // product layer dim
#define TH 400    // hidden width
#define BN_EPS 1e-3f

#define KT0 2     // layer-0 K=64  -> 2 chunks of K32
#define KTH 13    // layers 1/2 K=400 padded to 416 -> 13 chunks of K32

typedef __attribute__((ext_vector_type(8))) short bf16x8;
typedef __attribute__((ext_vector_type(4))) float f32x4;

// ---- fp32 -> bf16 hi/lo split ----
__device__ __forceinline__ ushort bf16_rn(float x) {
    __hip_bfloat16 h = __float2bfloat16(x);
    union { __hip_bfloat16 b; ushort u; } c; c.b = h; return c.u;
}
__device__ __forceinline__ void split2(float x, ushort& hi, ushort& lo) {
    unsigned xb = __float_as_uint(x);
    unsigned hb = xb & 0xFFFF0000u;
    hi = (ushort)(hb >> 16);
    lo = bf16_rn(x - __uint_as_float(hb));
}

// async global->LDS, 16 B per lane: LDS dst is wave-uniform base + lane*16,
// global src is per-lane.
__device__ __forceinline__ void gload_lds16(const void* g, void* l) {
    __builtin_amdgcn_global_load_lds(
        (const __attribute__((address_space(1))) void*)g,
        (__attribute__((address_space(3))) void*)l,
        16, 0, 0);
}

// MFMA 16x16x32 bf16 fragment layout. Panels: [tile16][kt32][lane 64][j 8]
// ushorts; one (tile,kt) chunk = 512 ushorts = 1 KB.
__device__ __forceinline__ size_t panel_idx(int p, int k, int KT) {
    int lane_ = (p & 15) + 16 * ((k >> 2) & 3);
    int j_    = (k & 3) + 4 * ((k >> 4) & 1);
    return (((size_t)((p >> 4) * KT + (k >> 5)) * 64) + lane_) * 8 + j_;
}

// ---------------------------------------------------------------------------
// Front kernel:
//  blocks [0,1024): gather (async gload_lds) + l_z (2d x 2r tile) + l_p -> A0
//  blocks [1024,1422): prepack W0/W1/W2 -> B panels; fold BN -> AC arrays
// ---------------------------------------------------------------------------
__global__ __launch_bounds__(256) void fused_front_kernel(
    const int*   __restrict__ fidx,
    const float* __restrict__ emb,
    const float* __restrict__ lin_w,
    const float* __restrict__ quad_w,
    const float* __restrict__ W0, const float* __restrict__ W1, const float* __restrict__ W2,
    const float* __restrict__ b0_, const float* __restrict__ g0_, const float* __restrict__ be0_,
    const float* __restrict__ rm0_, const float* __restrict__ rv0_,
    const float* __restrict__ b1_, const float* __restrict__ g1_, const float* __restrict__ be1_,
    const float* __restrict__ rm1_, const float* __restrict__ rv1_,
    const float* __restrict__ b2_, const float* __restrict__ g2_, const float* __restrict__ be2_,
    const float* __restrict__ rm2_, const float* __restrict__ rv2_,
    ushort* __restrict__ A0h, ushort* __restrict__ A0l,
    ushort* __restrict__ B0h, ushort* __restrict__ B0l,
    ushort* __restrict__ B1h, ushort* __restrict__ B1l,
    ushort* __restrict__ B2h, ushort* __restrict__ B2l,
    float* __restrict__ AC)
{
    if (blockIdx.x >= TB / 4) {
        int tid = (blockIdx.x - TB / 4) * 256 + threadIdx.x;
        const int NW0 = 64 * 112, NW = 416 * 112;
        if (tid < NW0 + 2 * NW) {
            const float* W; ushort *Ph, *Pl; int k, n4, K, KT;
            if (tid < NW0) {
                W = W0; Ph = B0h; Pl = B0l; k = tid / 112; n4 = tid % 112; K = 64; KT = KT0;
            } else if (tid < NW0 + NW) {
                int u = tid - NW0;
                W = W1; Ph = B1h; Pl = B1l; k = u / 112; n4 = u % 112; K = TH; KT = KTH;
            } else {
                int u = tid - NW0 - NW;
                W = W2; Ph = B2h; Pl = B2l; k = u / 112; n4 = u % 112; K = TH; KT = KTH;
            }
            int n0 = n4 * 4;
            float4 w = make_float4(0.f, 0.f, 0.f, 0.f);
            if (k < K && n0 < TH)
                w = *(const float4*)&W[(size_t)k * TH + n0];
            float vals[4] = {w.x, w.y, w.z, w.w};
            #pragma unroll
            for (int i = 0; i < 4; ++i) {
                ushort hi, lo; split2(vals[i], hi, lo);
                size_t idx = panel_idx(n0 + i, k, KT);
                Ph[idx] = hi; Pl[idx] = lo;
            }
        } else if (tid < NW0 + 2 * NW + 3 * 448) {
            int u = tid - NW0 - 2 * NW;
            int layer = u / 448, h = u % 448;
            const float *gp, *bep, *rmp, *rvp, *bp;
            if (layer == 0)      { gp = g0_; bep = be0_; rmp = rm0_; rvp = rv0_; bp = b0_; }
            else if (layer == 1) { gp = g1_; bep = be1_; rmp = rm1_; rvp = rv1_; bp = b1_; }
            else                 { gp = g2_; bep = be2_; rmp = rm2_; rvp = rv2_; bp = b2_; }
            float aj = 0.f, cj = 0.f;
            if (h < TH) {
                aj = gp[h] * rsqrtf(rvp[h] + BN_EPS);
                cj = (bp[h] - rmp[h]) * aj + bep[h];
            }
            AC[layer * 896 + h] = aj;
            AC[layer * 896 + 448 + h] = cj;
        }
        return;
    }

    // ---------------- gather + product path ----------------
    constexpr int R = 4;
    __shared__ float e_s[R][TN * TM];   // rows contiguous (required by gload_lds)
    __shared__ int   idx_s[R][TN];
    __shared__ float s_s[R][TN];

    const int t  = threadIdx.x;
    const int b0 = blockIdx.x * R;
    const int w  = t >> 6;

    if (t < R * TN) {
        int r = t / TN, n = t - r * TN;
        idx_s[r][n] = fidx[(b0 + r) * TN + n];
    }
    __syncthreads();

    // Gather via async global_load_lds (round-15 verified): k4 = t covers
    // [0,256); wave w's lanes contiguous 1 KB at e_s[r] + w*1024B; tail under
    // exec mask. One __syncthreads drains all loads.
    #pragma unroll
    for (int r = 0; r < R; ++r) {
        {
            int n = t >> 3;
            long long gb = (long long)idx_s[r][n] * TM + ((t & 7) << 2);
            gload_lds16(&emb[gb], &e_s[r][w * 256]);
        }
        if (t < 56) {
            int k4 = 256 + t;
            int n = k4 >> 3;
            long long gb = (long long)idx_s[r][n] * TM + ((k4 & 7) << 2);
            gload_lds16(&emb[gb], &e_s[r][1024]);
        }
    }
    __syncthreads();

    // l_z (2d x 2r tile): thread (dp = t>>4, rp = (t>>3)&1, j = t&7) computes
    // d = dp*2+{0,1} for rows r = rp*2+{0,1}. Per i: 2 LDS reads (was 4) +
    // 2 lw loads (same L2 traffic as 1 wider). Per-(d,r) FMA order and the
    // 8-lane j-shuffle tree are identical to round-2 -> bitwise-identical A0.
    {
        const int dp = t >> 4, rp = (t >> 3) & 1, j = t & 7;
        float acc[2][2] = {{0.f, 0.f}, {0.f, 0.f}};
        const float* lwb = lin_w + (size_t)(dp * 2) * (TN * TM) + j * 4;
        const float* e0  = &e_s[rp * 2][j * 4];
        const float* e1  = &e_s[rp * 2 + 1][j * 4];
        #pragma unroll 4
        for (int i = 0; i < TN; ++i) {
            float4 lwA = *(const float4*)&lwb[i * 32];
            float4 lwB = *(const float4*)&lwb[(size_t)(TN * TM) + i * 32];
            float4 eA  = *(const float4*)&e0[i * 32];
            float4 eB  = *(const float4*)&e1[i * 32];
            acc[0][0] = fmaf(lwA.x, eA.x, acc[0][0]);
            acc[0][0] = fmaf(lwA.y, eA.y, acc[0][0]);
            acc[0][0] = fmaf(lwA.z, eA.z, acc[0][0]);
            acc[0][0] = fmaf(lwA.w, eA.w, acc[0][0]);
            acc[0][1] = fmaf(lwA.x, eB.x, acc[0][1]);
            acc[0][1] = fmaf(lwA.y, eB.y, acc[0][1]);
            acc[0][1] = fmaf(lwA.z, eB.z, acc[0][1]);
            acc[0][1] = fmaf(lwA.w, eB.w, acc[0][1]);
            acc[1][0] = fmaf(lwB.x, eA.x, acc[1][0]);
            acc[1][0] = fmaf(lwB.y, eA.y, acc[1][0]);
            acc[1][0] = fmaf(lwB.z, eA.z, acc[1][0]);
            acc[1][0] = fmaf(lwB.w, eA.w, acc[1][0]);
            acc[1][1] = fmaf(lwB.x, eB.x, acc[1][1]);
            acc[1][1] = fmaf(lwB.y, eB.y, acc[1][1]);
            acc[1][1] = fmaf(lwB.z, eB.z, acc[1][1]);
            acc[1][1] = fmaf(lwB.w, eB.w, acc[1][1]);
        }
        #pragma unroll
        for (int off = 1; off < 8; off <<= 1)
            #pragma unroll
            for (int dd = 0; dd < 2; ++dd)
                #pragma unroll
                for (int rr = 0; rr < 2; ++rr)
                    acc[dd][rr] += __shfl_xor(acc[dd][rr], off);
        if (j == 0) {
            #pragma unroll
            for (int dd = 0; dd < 2; ++dd)
                #pragma unroll
                for (int rr = 0; rr < 2; ++rr) {
                    ushort hi, lo; split2(acc[dd][rr], hi, lo);
                    size_t idx = panel_idx(b0 + rp * 2 + rr, dp * 2 + dd, KT0);
                    A0h[idx] = hi; A0l[idx] = lo;
                }
        }
    }

    // s[n] = sum_m e^2
    {
        int r = t >> 6, lane = t & 63;
        if (lane < TN) {
            float s = 0.f;
            #pragma unroll
            for (int mm = 0; mm < TM; ++mm) {
                float v = e_s[r][lane * TM + ((lane + mm) & 31)];
                s = fmaf(v, v, s);
            }
            s_s[r][lane] = s;
        }
    }
    __syncthreads();

    // l_p
    if (t < R * TD) {
        int r = t >> 5, d = t & 31;
        float accv = 0.f;
        for (int n = 0; n < TN; ++n) {
            float q = quad_w[d * TN + n];
            accv = fmaf(s_s[r][n], q * q, accv);
        }
        ushort hi, lo; split2(accv, hi, lo);
        size_t idx = panel_idx(b0 + r, TD + d, KT0);
        A0h[idx] = hi; A0l[idx] = lo;
    }
}

// ---------------------------------------------------------------------------
// GEMM v7 (round-10 body, unchanged): 64x64 tile, 4 waves, XCD swizzle,
// per-kt LDS staging via global_load_lds (double-buffered).
// ---------------------------------------------------------------------------
template <int KT, int OUTMODE>
__global__ __launch_bounds__(256) void gemm_layer_v7(
    const ushort* __restrict__ Ah, const ushort* __restrict__ Al,
    const ushort* __restrict__ Bh, const ushort* __restrict__ Bl,
    const float* __restrict__ ACl,
    ushort* __restrict__ Nh, ushort* __restrict__ Nl,
    const float* __restrict__ Wout,
    float* __restrict__ P)
{
    __shared__ ushort stage[2][16 * 512];   // 2 x 16 KB double buffer

    const int lane = threadIdx.x & 63;
    const int wv   = threadIdx.x >> 6;      // 0..3
    const int msel = wv >> 1;               // M half
    const int nsel = wv & 1;                // N half

    // XCD-aware bijective swizzle over 448 blocks (bm 0..63, bn 0..6)
    const int orig = blockIdx.x;
    const int xcd  = orig & 7;
    const int slot = orig >> 3;             // 0..55
    const int bm   = (slot & 7) * 8 + xcd;  // 0..63
    const int bn   = slot >> 3;             // 0..6

    // Per-wave staging assignment: 4 chunks each
    const ushort* csrc[4];
    int coff[4];
    #pragma unroll
    for (int i = 0; i < 4; ++i) {
        int c = wv * 4 + i;
        bool isA = c < 8;
        int tl  = isA ? (c >> 1) : ((c - 8) >> 1);
        bool lo = c & 1;
        const ushort* base = isA ? (lo ? Al : Ah) : (lo ? Bl : Bh);
        int tileIdx = isA ? (bm * 4 + tl) : (bn * 4 + tl);
        csrc[i] = base + (size_t)tileIdx * KT * 512 + (size_t)lane * 8;
        coff[i] = c * 512;
    }

    f32x4 acc[2][2];
    #pragma unroll
    for (int m = 0; m < 2; ++m)
        #pragma unroll
        for (int n = 0; n < 2; ++n)
            acc[m][n] = (f32x4){0.f, 0.f, 0.f, 0.f};

    // prologue: stage kt=0 into buf0
    #pragma unroll
    for (int i = 0; i < 4; ++i)
        gload_lds16(csrc[i], &stage[0][coff[i]]);
    __syncthreads();

    for (int kt = 0; kt < KT; ++kt) {
        const int cur = kt & 1;
        if (kt + 1 < KT) {
            #pragma unroll
            for (int i = 0; i < 4; ++i)
                gload_lds16(csrc[i] + (size_t)(kt + 1) * 512,
                            &stage[cur ^ 1][coff[i]]);
        }
        const ushort* L = &stage[cur][0];
        bf16x8 ah[2], al[2], bh[2], bl[2];
        #pragma unroll
        for (int m = 0; m < 2; ++m) {
            int mt = msel * 2 + m;
            ah[m] = *(const bf16x8*)&L[(mt * 2 + 0) * 512 + lane * 8];
            al[m] = *(const bf16x8*)&L[(mt * 2 + 1) * 512 + lane * 8];
        }
        #pragma unroll
        for (int n = 0; n < 2; ++n) {
            int nt = nsel * 2 + n;
            bh[n] = *(const bf16x8*)&L[(8 + nt * 2 + 0) * 512 + lane * 8];
            bl[n] = *(const bf16x8*)&L[(8 + nt * 2 + 1) * 512 + lane * 8];
        }
        #pragma unroll
        for (int m = 0; m < 2; ++m)
            #pragma unroll
            for (int n = 0; n < 2; ++n) {
                acc[m][n] = __builtin_amdgcn_mfma_f32_16x16x32_bf16(ah[m], bh[n], acc[m][n], 0, 0, 0);
                acc[m][n] = __builtin_amdgcn_mfma_f32_16x16x32_bf16(ah[m], bl[n], acc[m][n], 0, 0, 0);
                acc[m][n] = __builtin_amdgcn_mfma_f32_16x16x32_bf16(al[m], bh[n], acc[m][n], 0, 0, 0);
            }
        __syncthreads();   // drains staged loads; protects buffer swap
    }

    const int col = lane & 15, rq = (lane >> 4) << 2;

    if constexpr (OUTMODE == 0) {
        float (*ysm)[68] = (float (*)[68])(void*)&stage[0][0];  // 17.4 KB alias
        #pragma unroll
        for (int m = 0; m < 2; ++m)
            #pragma unroll
            for (int n = 0; n < 2; ++n) {
                int h = bn * 64 + (nsel * 2 + n) * 16 + col;
                float aj = ACl[h], cj = ACl[448 + h];
                #pragma unroll
                for (int r = 0; r < 4; ++r)
                    ysm[msel * 32 + m * 16 + rq + r][(nsel * 2 + n) * 16 + col] =
                        fmaxf(fmaf(acc[m][n][r], aj, cj), 0.f);
            }
        __syncthreads();

        const int ck = wv & 1;
        const int kt32 = bn * 2 + ck;
        if (kt32 < KTH) {
            #pragma unroll
            for (int mi = 0; mi < 2; ++mi) {
                int mtl = (wv >> 1) * 2 + mi;    // 0..3
                int row_l = mtl * 16 + (lane & 15);
                int kb = ck * 32 + rq;
                float4 v0 = *(const float4*)&ysm[row_l][kb];
                float4 v1 = *(const float4*)&ysm[row_l][kb + 16];
                ushort h_[8], l_[8];
                split2(v0.x, h_[0], l_[0]); split2(v0.y, h_[1], l_[1]);
                split2(v0.z, h_[2], l_[2]); split2(v0.w, h_[3], l_[3]);
                split2(v1.x, h_[4], l_[4]); split2(v1.y, h_[5], l_[5]);
                split2(v1.z, h_[6], l_[6]); split2(v1.w, h_[7], l_[7]);
                uint4 H, L2;
                H.x = (uint)h_[0] | ((uint)h_[1] << 16);
                H.y = (uint)h_[2] | ((uint)h_[3] << 16);
                H.z = (uint)h_[4] | ((uint)h_[5] << 16);
                H.w = (uint)h_[6] | ((uint)h_[7] << 16);
                L2.x = (uint)l_[0] | ((uint)l_[1] << 16);
                L2.y = (uint)l_[2] | ((uint)l_[3] << 16);
                L2.z = (uint)l_[4] | ((uint)l_[5] << 16);
                L2.w = (uint)l_[6] | ((uint)l_[7] << 16);
                size_t base = (((size_t)(bm * 4 + mtl) * KTH + kt32) * 64 + lane) * 8;
                *(uint4*)(Nh + base) = H;
                *(uint4*)(Nl + base) = L2;
            }
        }
    } else {
        // Fused final-layer epilogue: y = relu(bn(acc)); partial = sum_h y*Wout[h]
        float partial[2][4] = {{0.f,0.f,0.f,0.f},{0.f,0.f,0.f,0.f}};
        #pragma unroll
        for (int m = 0; m < 2; ++m)
            #pragma unroll
            for (int n = 0; n < 2; ++n) {
                int h = bn * 64 + (nsel * 2 + n) * 16 + col;
                float aj = ACl[h], cj = ACl[448 + h];
                float wv_ = (h < TH) ? Wout[h] : 0.f;
                #pragma unroll
                for (int r = 0; r < 4; ++r) {
                    float y = fmaxf(fmaf(acc[m][n][r], aj, cj), 0.f);
                    partial[m][r] = fmaf(y, wv_, partial[m][r]);
                }
            }
        #pragma unroll
        for (int off = 1; off < 16; off <<= 1)
            #pragma unroll
            for (int m = 0; m < 2; ++m)
                #pragma unroll
                for (int r = 0; r < 4; ++r)
                    partial[m][r] += __shfl_xor(partial[m][r], off);
        if (col == 0) {
            #pragma unroll
            for (int m = 0; m < 2; ++m)
                #pragma unroll
                for (int r = 0; r < 4; ++r)
                    P[(size_t)(bm * 64 + msel * 32 + m * 16 + rq + r) * 16
                      + bn * 2 + nsel] = partial[m][r];
        }
    }
}

// ---------------------------------------------------------------------------
// fin: out[row] = sigmoid(sum_{i<14} P[row][i] + bout), float4 loads
// ---------------------------------------------------------------------------
__global__ __launch_bounds__(256) void fin_kernel(
    const float* __restrict__ P, const float* __restrict__ bout,
    float* __restrict__ out)
{
    int row = blockIdx.x * 256 + threadIdx.x;
    const float4* p = (const float4*)(P + (size_t)row * 16);
    float4 p0 = p[0], p1 = p[1], p2 = p[2], p3 = p[3];
    float s = bout[0]
            + p0.x + p0.y + p0.z + p0.w
            + p1.x + p1.y + p1.z + p1.w
            + p2.x + p2.y + p2.z + p2.w
            + p3.x + p3.y;
    out[row] = 1.f / (1.f + expf(-s));
}

// ---------------------------------------------------------------------------
extern "C" void kernel_launch(void* const* d_in, const int* in_sizes, int n_in,
                              void* d_out, int out_size, void* d_ws, size_t ws_size,
                              hipStream_t stream) {
    const int*   fidx   = (const int*)  d_in[0];
    const float* emb    = (const float*)d_in[2];
    const float* lin_w  = (const float*)d_in[3];
    const float* quad_w = (const float*)d_in[4];

    const float* W0  = (const float*)d_in[5];
    const float* b0  = (const float*)d_in[6];
    const float* g0  = (const float*)d_in[7];
    const float* be0 = (const float*)d_in[8];
    const float* rm0 = (const float*)d_in[9];
    const float* rv0 = (const float*)d_in[10];

    const float* W1  = (const float*)d_in[11];
    const float* b1  = (const float*)d_in[12];
    const float* g1  = (const float*)d_in[13];
    const float* be1 = (const float*)d_in[14];
    const float* rm1 = (const float*)d_in[15];
    const float* rv1 = (const float*)d_in[16];

    const float* W2  = (const float*)d_in[17];
    const float* b2  = (const float*)d_in[18];
    const float* g2  = (const float*)d_in[19];
    const float* be2 = (const float*)d_in[20];
    const float* rm2 = (const float*)d_in[21];
    const float* rv2 = (const float*)d_in[22];

    const float* Wout = (const float*)d_in[23];
    const float* bout = (const float*)d_in[24];

    const size_t SZ_A0 = (size_t)256 * KT0 * 512;
    const size_t SZ_A  = (size_t)256 * KTH * 512;
    const size_t SZ_B0 = (size_t)28  * KT0 * 512;
    const size_t SZ_B  = (size_t)28  * KTH * 512;

    ushort* p = (ushort*)d_ws;
    ushort *A0h = p; p += SZ_A0; ushort *A0l = p; p += SZ_A0;
    ushort *A1h = p; p += SZ_A;  ushort *A1l = p; p += SZ_A;
    ushort *A2h = p; p += SZ_A;  ushort *A2l = p; p += SZ_A;
    ushort *B0h = p; p += SZ_B0; ushort *B0l = p; p += SZ_B0;
    ushort *B1h = p; p += SZ_B;  ushort *B1l = p; p += SZ_B;
    ushort *B2h = p; p += SZ_B;  ushort *B2l = p; p += SZ_B;
    float*  AC  = (float*)p;                 // 3 * 896 floats
    float*  Pst = AC + 3 * 896;              // 4096 x 16 partials

    fused_front_kernel<<<TB / 4 + 398, 256, 0, stream>>>(
        fidx, emb, lin_w, quad_w, W0, W1, W2,
        b0, g0, be0, rm0, rv0,
        b1, g1, be1, rm1, rv1,
        b2, g2, be2, rm2, rv2,
        A0h, A0l, B0h, B0l, B1h, B1l, B2h, B2l, AC);

    gemm_layer_v7<KT0, 0><<<448, 256, 0, stream>>>(
        A0h, A0l, B0h, B0l, AC + 0, A1h, A1l, nullptr, nullptr);
    gemm_layer_v7<KTH, 0><<<448, 256, 0, stream>>>(
        A1h, A1l, B1h, B1l, AC + 896, A2h, A2l, nullptr, nullptr);
    gemm_layer_v7<KTH, 1><<<448, 256, 0, stream>>>(
        A2h, A2l, B2h, B2l, AC + 1792, nullptr, nullptr, Wout, Pst);

    fin_kernel<<<TB / 256, 256, 0, stream>>>(Pst, bout, (float*)d_out);
}

// Round 18
// 47.266 us; speedup vs baseline: 1.2039x; 1.0357x over previous
//
#include <hip/hip_runtime.h>
#include <hip/hip_bf16.h>
#include <math.h>

#define TB 4096   // batch
#define TN 39     // fields
#define TM 32     // embed dim
#define TD 32     // product layer dim
#define TH 400    // hidden width
#define BN_EPS 1e-3f

#define KT0 2     // layer-0 K=64  -> 2 chunks of K32
#define KTH 13    // layers 1/2 K=400 padded to 416 -> 13 chunks of K32

typedef __attribute__((ext_vector_type(8))) short bf16x8;
typedef __attribute__((ext_vector_type(4))) float f32x4;

// ---- fp32 -> bf16 hi/lo split ----
__device__ __forceinline__ ushort bf16_rn(float x) {
    __hip_bfloat16 h = __float2bfloat16(x);
    union { __hip_bfloat16 b; ushort u; } c; c.b = h; return c.u;
}
__device__ __forceinline__ void split2(float x, ushort& hi, ushort& lo) {
    unsigned xb = __float_as_uint(x);
    unsigned hb = xb & 0xFFFF0000u;
    hi = (ushort)(hb >> 16);
    lo = bf16_rn(x - __uint_as_float(hb));
}

// async global->LDS, 16 B per lane: LDS dst is wave-uniform base + lane*16,
// global src is per-lane (base + lane*16 passed in).
__device__ __forceinline__ void gload_lds16(const ushort* g, ushort* l) {
    __builtin_amdgcn_global_load_lds(
        (const __attribute__((address_space(1))) void*)g,
        (__attribute__((address_space(3))) void*)l,
        16, 0, 0);
}

// MFMA 16x16x32 bf16 fragment layout. Panels: [tile16][kt32][lane 64][j 8]
// ushorts; one (tile,kt) chunk = 512 ushorts = 1 KB.
__device__ __forceinline__ size_t panel_idx(int p, int k, int KT) {
    int lane_ = (p & 15) + 16 * ((k >> 2) & 3);
    int j_    = (k & 3) + 4 * ((k >> 4) & 1);
    return (((size_t)((p >> 4) * KT + (k >> 5)) * 64) + lane_) * 8 + j_;
}

// ---------------------------------------------------------------------------
// Front kernel (round-2/8-verified R=4 body):
//  blocks [0,1024): gather + l_z + l_p -> A0 panels (hi/lo)
//  blocks [1024,1422): prepack W0/W1/W2 -> B panels; fold BN -> AC arrays
// ---------------------------------------------------------------------------
__global__ __launch_bounds__(256) void fused_front_kernel(
    const int*   __restrict__ fidx,
    const float* __restrict__ emb,
    const float* __restrict__ lin_w,
    const float* __restrict__ quad_w,
    const float* __restrict__ W0, const float* __restrict__ W1, const float* __restrict__ W2,
    const float* __restrict__ b0_, const float* __restrict__ g0_, const float* __restrict__ be0_,
    const float* __restrict__ rm0_, const float* __restrict__ rv0_,
    const float* __restrict__ b1_, const float* __restrict__ g1_, const float* __restrict__ be1_,
    const float* __restrict__ rm1_, const float* __restrict__ rv1_,
    const float* __restrict__ b2_, const float* __restrict__ g2_, const float* __restrict__ be2_,
    const float* __restrict__ rm2_, const float* __restrict__ rv2_,
    ushort* __restrict__ A0h, ushort* __restrict__ A0l,
    ushort* __restrict__ B0h, ushort* __restrict__ B0l,
    ushort* __restrict__ B1h, ushort* __restrict__ B1l,
    ushort* __restrict__ B2h, ushort* __restrict__ B2l,
    float* __restrict__ AC)
{
    if (blockIdx.x >= TB / 4) {
        int tid = (blockIdx.x - TB / 4) * 256 + threadIdx.x;
        const int NW0 = 64 * 112, NW = 416 * 112;
        if (tid < NW0 + 2 * NW) {
            const float* W; ushort *Ph, *Pl; int k, n4, K, KT;
            if (tid < NW0) {
                W = W0; Ph = B0h; Pl = B0l; k = tid / 112; n4 = tid % 112; K = 64; KT = KT0;
            } else if (tid < NW0 + NW) {
                int u = tid - NW0;
                W = W1; Ph = B1h; Pl = B1l; k = u / 112; n4 = u % 112; K = TH; KT = KTH;
            } else {
                int u = tid - NW0 - NW;
                W = W2; Ph = B2h; Pl = B2l; k = u / 112; n4 = u % 112; K = TH; KT = KTH;
            }
            int n0 = n4 * 4;
            float4 w = make_float4(0.f, 0.f, 0.f, 0.f);
            if (k < K && n0 < TH)
                w = *(const float4*)&W[(size_t)k * TH + n0];
            float vals[4] = {w.x, w.y, w.z, w.w};
            #pragma unroll
            for (int i = 0; i < 4; ++i) {
                ushort hi, lo; split2(vals[i], hi, lo);
                size_t idx = panel_idx(n0 + i, k, KT);
                Ph[idx] = hi; Pl[idx] = lo;
            }
        } else if (tid < NW0 + 2 * NW + 3 * 448) {
            int u = tid - NW0 - 2 * NW;
            int layer = u / 448, h = u % 448;
            const float *gp, *bep, *rmp, *rvp, *bp;
            if (layer == 0)      { gp = g0_; bep = be0_; rmp = rm0_; rvp = rv0_; bp = b0_; }
            else if (layer == 1) { gp = g1_; bep = be1_; rmp = rm1_; rvp = rv1_; bp = b1_; }
            else                 { gp = g2_; bep = be2_; rmp = rm2_; rvp = rv2_; bp = b2_; }
            float aj = 0.f, cj = 0.f;
            if (h < TH) {
                aj = gp[h] * rsqrtf(rvp[h] + BN_EPS);
                cj = (bp[h] - rmp[h]) * aj + bep[h];
            }
            AC[layer * 896 + h] = aj;
            AC[layer * 896 + 448 + h] = cj;
        }
        return;
    }

    // ---------------- gather + product path ----------------
    constexpr int R = 4;
    __shared__ float e_s[R][TN * TM];
    __shared__ int   idx_s[R][TN];
    __shared__ float s_s[R][TN];

    const int t  = threadIdx.x;
    const int b0 = blockIdx.x * R;

    if (t < R * TN) {
        int r = t / TN, n = t - r * TN;
        idx_s[r][n] = fidx[(b0 + r) * TN + n];
    }
    __syncthreads();

    for (int r = 0; r < R; ++r) {
        for (int k4 = t; k4 < TN * TM / 4; k4 += 256) {
            int n = k4 >> 3;
            long long base = (long long)idx_s[r][n] * TM + ((k4 & 7) << 2);
            *(float4*)&e_s[r][k4 * 4] = *(const float4*)&emb[base];
        }
    }
    __syncthreads();

    // l_z
    {
        const int d = t >> 3, j = t & 7;
        float acc[R] = {0.f, 0.f, 0.f, 0.f};
        const float* lw_base = lin_w + d * (TN * TM);
        #pragma unroll 4
        for (int i = 0; i < TN; ++i) {
            float4 lw = *(const float4*)&lw_base[i * 32 + j * 4];
            #pragma unroll
            for (int r = 0; r < R; ++r) {
                float4 e4 = *(const float4*)&e_s[r][i * 32 + j * 4];
                acc[r] = fmaf(lw.x, e4.x, acc[r]);
                acc[r] = fmaf(lw.y, e4.y, acc[r]);
                acc[r] = fmaf(lw.z, e4.z, acc[r]);
                acc[r] = fmaf(lw.w, e4.w, acc[r]);
            }
        }
        #pragma unroll
        for (int off = 1; off < 8; off <<= 1)
            #pragma unroll
            for (int r = 0; r < R; ++r)
                acc[r] += __shfl_xor(acc[r], off);
        if (j == 0) {
            #pragma unroll
            for (int r = 0; r < R; ++r) {
                ushort hi, lo; split2(acc[r], hi, lo);
                size_t idx = panel_idx(b0 + r, d, KT0);
                A0h[idx] = hi; A0l[idx] = lo;
            }
        }
    }

    // s[n] = sum_m e^2
    {
        int r = t >> 6, lane = t & 63;
        if (lane < TN) {
            float s = 0.f;
            #pragma unroll
            for (int mm = 0; mm < TM; ++mm) {
                float v = e_s[r][lane * TM + ((lane + mm) & 31)];
                s = fmaf(v, v, s);
            }
            s_s[r][lane] = s;
        }
    }
    __syncthreads();

    // l_p
    if (t < R * TD) {
        int r = t >> 5, d = t & 31;
        float accv = 0.f;
        for (int n = 0; n < TN; ++n) {
            float q = quad_w[d * TN + n];
            accv = fmaf(s_s[r][n], q * q, accv);
        }
        ushort hi, lo; split2(accv, hi, lo);
        size_t idx = panel_idx(b0 + r, TD + d, KT0);
        A0h[idx] = hi; A0l[idx] = lo;
    }
}

// ---------------------------------------------------------------------------
// GEMM v7: 64x64 tile, 4 waves (2M x 2N quadrants of 32x32), XCD swizzle.
// Per-kt 16 KB of A/B chunks staged into LDS once per block via
// global_load_lds (double-buffered, one barrier/kt) -> halves L2 traffic.
// OUTMODE 0: BN+ReLU -> repack into next layer's A panels (ysm aliased onto
// the stage buffer). OUTMODE 1: BN+ReLU -> Wout dot -> partials to P.
// ---------------------------------------------------------------------------
template <int KT, int OUTMODE>
__global__ __launch_bounds__(256) void gemm_layer_v7(
    const ushort* __restrict__ Ah, const ushort* __restrict__ Al,
    const ushort* __restrict__ Bh, const ushort* __restrict__ Bl,
    const float* __restrict__ ACl,
    ushort* __restrict__ Nh, ushort* __restrict__ Nl,
    const float* __restrict__ Wout,
    float* __restrict__ P)
{
    __shared__ ushort stage[2][16 * 512];   // 2 x 16 KB double buffer

    const int lane = threadIdx.x & 63;
    const int wv   = threadIdx.x >> 6;      // 0..3
    const int msel = wv >> 1;               // M half
    const int nsel = wv & 1;                // N half

    // XCD-aware bijective swizzle over 448 blocks (bm 0..63, bn 0..6)
    const int orig = blockIdx.x;
    const int xcd  = orig & 7;
    const int slot = orig >> 3;             // 0..55
    const int bm   = (slot & 7) * 8 + xcd;  // 0..63
    const int bn   = slot >> 3;             // 0..6

    // Per-wave staging assignment: 4 chunks each
    const ushort* csrc[4];
    int coff[4];
    #pragma unroll
    for (int i = 0; i < 4; ++i) {
        int c = wv * 4 + i;
        bool isA = c < 8;
        int tl  = isA ? (c >> 1) : ((c - 8) >> 1);
        bool lo = c & 1;
        const ushort* base = isA ? (lo ? Al : Ah) : (lo ? Bl : Bh);
        int tileIdx = isA ? (bm * 4 + tl) : (bn * 4 + tl);
        csrc[i] = base + (size_t)tileIdx * KT * 512 + (size_t)lane * 8;
        coff[i] = c * 512;
    }

    f32x4 acc[2][2];
    #pragma unroll
    for (int m = 0; m < 2; ++m)
        #pragma unroll
        for (int n = 0; n < 2; ++n)
            acc[m][n] = (f32x4){0.f, 0.f, 0.f, 0.f};

    // prologue: stage kt=0 into buf0
    #pragma unroll
    for (int i = 0; i < 4; ++i)
        gload_lds16(csrc[i], &stage[0][coff[i]]);
    __syncthreads();

    for (int kt = 0; kt < KT; ++kt) {
        const int cur = kt & 1;
        if (kt + 1 < KT) {
            #pragma unroll
            for (int i = 0; i < 4; ++i)
                gload_lds16(csrc[i] + (size_t)(kt + 1) * 512,
                            &stage[cur ^ 1][coff[i]]);
        }
        const ushort* L = &stage[cur][0];
        bf16x8 ah[2], al[2], bh[2], bl[2];
        #pragma unroll
        for (int m = 0; m < 2; ++m) {
            int mt = msel * 2 + m;
            ah[m] = *(const bf16x8*)&L[(mt * 2 + 0) * 512 + lane * 8];
            al[m] = *(const bf16x8*)&L[(mt * 2 + 1) * 512 + lane * 8];
        }
        #pragma unroll
        for (int n = 0; n < 2; ++n) {
            int nt = nsel * 2 + n;
            bh[n] = *(const bf16x8*)&L[(8 + nt * 2 + 0) * 512 + lane * 8];
            bl[n] = *(const bf16x8*)&L[(8 + nt * 2 + 1) * 512 + lane * 8];
        }
        #pragma unroll
        for (int m = 0; m < 2; ++m)
            #pragma unroll
            for (int n = 0; n < 2; ++n) {
                acc[m][n] = __builtin_amdgcn_mfma_f32_16x16x32_bf16(ah[m], bh[n], acc[m][n], 0, 0, 0);
                acc[m][n] = __builtin_amdgcn_mfma_f32_16x16x32_bf16(ah[m], bl[n], acc[m][n], 0, 0, 0);
                acc[m][n] = __builtin_amdgcn_mfma_f32_16x16x32_bf16(al[m], bh[n], acc[m][n], 0, 0, 0);
            }
        __syncthreads();   // drains staged loads; protects buffer swap
    }

    const int col = lane & 15, rq = (lane >> 4) << 2;

    if constexpr (OUTMODE == 0) {
        float (*ysm)[68] = (float (*)[68])(void*)&stage[0][0];  // 17.4 KB alias
        #pragma unroll
        for (int m = 0; m < 2; ++m)
            #pragma unroll
            for (int n = 0; n < 2; ++n) {
                int h = bn * 64 + (nsel * 2 + n) * 16 + col;
                float aj = ACl[h], cj = ACl[448 + h];
                #pragma unroll
                for (int r = 0; r < 4; ++r)
                    ysm[msel * 32 + m * 16 + rq + r][(nsel * 2 + n) * 16 + col] =
                        fmaxf(fmaf(acc[m][n][r], aj, cj), 0.f);
            }
        __syncthreads();

        const int ck = wv & 1;
        const int kt32 = bn * 2 + ck;
        if (kt32 < KTH) {
            #pragma unroll
            for (int mi = 0; mi < 2; ++mi) {
                int mtl = (wv >> 1) * 2 + mi;    // 0..3
                int row_l = mtl * 16 + (lane & 15);
                int kb = ck * 32 + rq;
                float4 v0 = *(const float4*)&ysm[row_l][kb];
                float4 v1 = *(const float4*)&ysm[row_l][kb + 16];
                ushort h_[8], l_[8];
                split2(v0.x, h_[0], l_[0]); split2(v0.y, h_[1], l_[1]);
                split2(v0.z, h_[2], l_[2]); split2(v0.w, h_[3], l_[3]);
                split2(v1.x, h_[4], l_[4]); split2(v1.y, h_[5], l_[5]);
                split2(v1.z, h_[6], l_[6]); split2(v1.w, h_[7], l_[7]);
                uint4 H, L2;
                H.x = (uint)h_[0] | ((uint)h_[1] << 16);
                H.y = (uint)h_[2] | ((uint)h_[3] << 16);
                H.z = (uint)h_[4] | ((uint)h_[5] << 16);
                H.w = (uint)h_[6] | ((uint)h_[7] << 16);
                L2.x = (uint)l_[0] | ((uint)l_[1] << 16);
                L2.y = (uint)l_[2] | ((uint)l_[3] << 16);
                L2.z = (uint)l_[4] | ((uint)l_[5] << 16);
                L2.w = (uint)l_[6] | ((uint)l_[7] << 16);
                size_t base = (((size_t)(bm * 4 + mtl) * KTH + kt32) * 64 + lane) * 8;
                *(uint4*)(Nh + base) = H;
                *(uint4*)(Nl + base) = L2;
            }
        }
    } else {
        // Fused final-layer epilogue: y = relu(bn(acc)); partial = sum_h y*Wout[h]
        float partial[2][4] = {{0.f,0.f,0.f,0.f},{0.f,0.f,0.f,0.f}};
        #pragma unroll
        for (int m = 0; m < 2; ++m)
            #pragma unroll
            for (int n = 0; n < 2; ++n) {
                int h = bn * 64 + (nsel * 2 + n) * 16 + col;
                float aj = ACl[h], cj = ACl[448 + h];
                float wv_ = (h < TH) ? Wout[h] : 0.f;
                #pragma unroll
                for (int r = 0; r < 4; ++r) {
                    float y = fmaxf(fmaf(acc[m][n][r], aj, cj), 0.f);
                    partial[m][r] = fmaf(y, wv_, partial[m][r]);
                }
            }
        #pragma unroll
        for (int off = 1; off < 16; off <<= 1)
            #pragma unroll
            for (int m = 0; m < 2; ++m)
                #pragma unroll
                for (int r = 0; r < 4; ++r)
                    partial[m][r] += __shfl_xor(partial[m][r], off);
        if (col == 0) {
            #pragma unroll
            for (int m = 0; m < 2; ++m)
                #pragma unroll
                for (int r = 0; r < 4; ++r)
                    P[(size_t)(bm * 64 + msel * 32 + m * 16 + rq + r) * 16
                      + bn * 2 + nsel] = partial[m][r];
        }
    }
}

// ---------------------------------------------------------------------------
// fin: out[row] = sigmoid(sum_{i<14} P[row][i] + bout), float4 loads
// ---------------------------------------------------------------------------
__global__ __launch_bounds__(256) void fin_kernel(
    const float* __restrict__ P, const float* __restrict__ bout,
    float* __restrict__ out)
{
    int row = blockIdx.x * 256 + threadIdx.x;
    const float4* p = (const float4*)(P + (size_t)row * 16);
    float4 p0 = p[0], p1 = p[1], p2 = p[2], p3 = p[3];
    float s = bout[0]
            + p0.x + p0.y + p0.z + p0.w
            + p1.x + p1.y + p1.z + p1.w
            + p2.x + p2.y + p2.z + p2.w
            + p3.x + p3.y;
    out[row] = 1.f / (1.f + expf(-s));
}

// ---------------------------------------------------------------------------
extern "C" void kernel_launch(void* const* d_in, const int* in_sizes, int n_in,
                              void* d_out, int out_size, void* d_ws, size_t ws_size,
                              hipStream_t stream) {
    const int*   fidx   = (const int*)  d_in[0];
    const float* emb    = (const float*)d_in[2];
    const float* lin_w  = (const float*)d_in[3];
    const float* quad_w = (const float*)d_in[4];

    const float* W0  = (const float*)d_in[5];
    const float* b0  = (const float*)d_in[6];
    const float* g0  = (const float*)d_in[7];
    const float* be0 = (const float*)d_in[8];
    const float* rm0 = (const float*)d_in[9];
    const float* rv0 = (const float*)d_in[10];

    const float* W1  = (const float*)d_in[11];
    const float* b1  = (const float*)d_in[12];
    const float* g1  = (const float*)d_in[13];
    const float* be1 = (const float*)d_in[14];
    const float* rm1 = (const float*)d_in[15];
    const float* rv1 = (const float*)d_in[16];

    const float* W2  = (const float*)d_in[17];
    const float* b2  = (const float*)d_in[18];
    const float* g2  = (const float*)d_in[19];
    const float* be2 = (const float*)d_in[20];
    const float* rm2 = (const float*)d_in[21];
    const float* rv2 = (const float*)d_in[22];

    const float* Wout = (const float*)d_in[23];
    const float* bout = (const float*)d_in[24];

    const size_t SZ_A0 = (size_t)256 * KT0 * 512;
    const size_t SZ_A  = (size_t)256 * KTH * 512;
    const size_t SZ_B0 = (size_t)28  * KT0 * 512;
    const size_t SZ_B  = (size_t)28  * KTH * 512;

    ushort* p = (ushort*)d_ws;
    ushort *A0h = p; p += SZ_A0; ushort *A0l = p; p += SZ_A0;
    ushort *A1h = p; p += SZ_A;  ushort *A1l = p; p += SZ_A;
    ushort *A2h = p; p += SZ_A;  ushort *A2l = p; p += SZ_A;
    ushort *B0h = p; p += SZ_B0; ushort *B0l = p; p += SZ_B0;
    ushort *B1h = p; p += SZ_B;  ushort *B1l = p; p += SZ_B;
    ushort *B2h = p; p += SZ_B;  ushort *B2l = p; p += SZ_B;
    float*  AC  = (float*)p;                 // 3 * 896 floats
    float*  Pst = AC + 3 * 896;              // 4096 x 16 partials

    fused_front_kernel<<<TB / 4 + 398, 256, 0, stream>>>(
        fidx, emb, lin_w, quad_w, W0, W1, W2,
        b0, g0, be0, rm0, rv0,
        b1, g1, be1, rm1, rv1,
        b2, g2, be2, rm2, rv2,
        A0h, A0l, B0h, B0l, B1h, B1l, B2h, B2l, AC);

    gemm_layer_v7<KT0, 0><<<448, 256, 0, stream>>>(
        A0h, A0l, B0h, B0l, AC + 0, A1h, A1l, nullptr, nullptr);
    gemm_layer_v7<KTH, 0><<<448, 256, 0, stream>>>(
        A1h, A1l, B1h, B1l, AC + 896, A2h, A2l, nullptr, nullptr);
    gemm_layer_v7<KTH, 1><<<448, 256, 0, stream>>>(
        A2h, A2l, B2h, B2l, AC + 1792, nullptr, nullptr, Wout, Pst);

    fin_kernel<<<TB / 256, 256, 0, stream>>>(Pst, bout, (float*)d_out);
}